// Round 1
// baseline (278.920 us; speedup 1.0000x reference)
//
#include <hip/hip_runtime.h>
#include <math.h>

// Problem: Magnus-0 midpoint propagation of a damped oscillator.
//   out[0] = x0;  out[i+1] = E_i @ out[i],  E_i = expm(dt_i * A(t_mid_i)) (2x2)
// Structure: associative scan over 2x2 matrices.
//   K1: E_j per step (parallel, fp64 math -> fp32 store)
//   K2: chunk products (64 steps/chunk) + serial prefix scan -> Q_c
//   K3: per (chunk, column-group) block: x_start = Q_c x0, iterate chunk, write rows.
// HBM-write-bound: 256 MiB output -> ~48 us floor at ~5.5 TB/s.

#define CS  64     // time steps per chunk (nsteps <= CS*256 assumed; T=8192 here)
#define TPB 256

// ---------------- K1: per-step propagators ----------------
__global__ void compute_E(const float* __restrict__ t,
                          const float* __restrict__ p_w2,
                          const float* __restrict__ p_g0,
                          const float* __restrict__ p_gamp,
                          const float* __restrict__ p_od,
                          float4* __restrict__ E, int nsteps) {
    int j = blockIdx.x * blockDim.x + threadIdx.x;
    if (j >= nsteps) return;
    double w2 = (double)p_w2[0], g0 = (double)p_g0[0];
    double gamp = (double)p_gamp[0], od = (double)p_od[0];
    double t0 = (double)t[j], t1 = (double)t[j + 1];
    double dt = t1 - t0;
    double tm = t0 + 0.5 * dt;
    double gamma = g0 * (1.0 + gamp * sin(od * tm));
    // M = [[0, dt], [-w2*dt, -gamma*dt]]
    double m = -0.5 * gamma * dt;            // tr(M)/2
    double delta = m * m - w2 * dt * dt;     // m^2 - det(M)
    double s = sqrt(fabs(delta));
    double ss = fmax(s, 1e-12);
    double f, g;
    if (delta >= 0.0) { f = cosh(s); g = sinh(ss) / ss; }
    else              { f = cos(s);  g = sin(ss) / ss;  }
    double em = exp(m);
    // N = M - m*I = [[-m, dt], [-w2*dt, m]]
    float4 e;
    e.x = (float)(em * (f - g * m));
    e.y = (float)(em * (g * dt));
    e.z = (float)(em * (-g * w2 * dt));
    e.w = (float)(em * (f + g * m));
    E[j] = e;
}

// ---------------- K2: chunk products + serial prefix scan ----------------
__global__ void chunk_scan(const float4* __restrict__ E,
                           float4* __restrict__ Q,
                           int nsteps, int nch) {
    __shared__ double Ms[TPB][4];            // 8 KB
    int c = threadIdx.x;
    if (c < nch) {
        double m00 = 1, m01 = 0, m10 = 0, m11 = 1;
        int j0 = c * CS;
        int j1 = min(j0 + CS, nsteps);
        for (int j = j0; j < j1; ++j) {
            float4 e = E[j];
            double e00 = e.x, e01 = e.y, e10 = e.z, e11 = e.w;
            double n00 = e00 * m00 + e01 * m10;   // M <- E_j * M (left-apply)
            double n01 = e00 * m01 + e01 * m11;
            double n10 = e10 * m00 + e11 * m10;
            double n11 = e10 * m01 + e11 * m11;
            m00 = n00; m01 = n01; m10 = n10; m11 = n11;
        }
        Ms[c][0] = m00; Ms[c][1] = m01; Ms[c][2] = m10; Ms[c][3] = m11;
    }
    __syncthreads();
    if (threadIdx.x == 0) {
        double q00 = 1, q01 = 0, q10 = 0, q11 = 1;
        for (int cc = 0; cc < nch; ++cc) {
            Q[cc] = make_float4((float)q00, (float)q01, (float)q10, (float)q11);
            double a00 = Ms[cc][0], a01 = Ms[cc][1], a10 = Ms[cc][2], a11 = Ms[cc][3];
            double n00 = a00 * q00 + a01 * q10;   // Q <- M_c * Q
            double n01 = a00 * q01 + a01 * q11;
            double n10 = a10 * q00 + a11 * q10;
            double n11 = a10 * q01 + a11 * q11;
            q00 = n00; q01 = n01; q10 = n10; q11 = n11;
        }
    }
}

// ---------------- K3: propagate + write all rows ----------------
__global__ __launch_bounds__(TPB) void propagate(
        const float4* __restrict__ E,
        const float4* __restrict__ Q,
        const float* __restrict__ x0,
        float* __restrict__ out,
        int nsteps, int B, int bgroups) {
    __shared__ float4 Es[CS];                // 1 KB
    int c  = blockIdx.x / bgroups;
    int bg = blockIdx.x % bgroups;
    int b  = bg * TPB + threadIdx.x;
    int j0 = c * CS;
    int n  = min(CS, nsteps - j0);
    if (threadIdx.x < n) Es[threadIdx.x] = E[j0 + threadIdx.x];
    __syncthreads();
    if (b >= B) return;

    float4 q = Q[c];                         // wave-uniform broadcast
    float xa0 = x0[b], xb0 = x0[B + b];
    float xa = q.x * xa0 + q.y * xb0;
    float xb = q.z * xa0 + q.w * xb0;

    if (c == 0) {                            // row 0 = x0 verbatim
        out[b] = xa0;
        out[B + b] = xb0;
    }

    float* o = out + (size_t)(j0 + 1) * 2 * (size_t)B + b;
    #pragma unroll 4
    for (int jj = 0; jj < n; ++jj) {
        float4 e = Es[jj];
        float na = e.x * xa + e.y * xb;
        float nb = e.z * xa + e.w * xb;
        xa = na; xb = nb;
        o[0] = xa;
        o[B] = xb;
        o += 2 * B;
    }
}

extern "C" void kernel_launch(void* const* d_in, const int* in_sizes, int n_in,
                              void* d_out, int out_size, void* d_ws, size_t ws_size,
                              hipStream_t stream) {
    const float* t    = (const float*)d_in[0];
    const float* x0   = (const float*)d_in[1];
    const float* w2   = (const float*)d_in[2];
    const float* g0   = (const float*)d_in[3];
    const float* gamp = (const float*)d_in[4];
    const float* od   = (const float*)d_in[5];
    float* out = (float*)d_out;

    const int T = in_sizes[0];
    const int B = in_sizes[1] / 2;
    const int nsteps = T - 1;
    const int nch = (nsteps + CS - 1) / CS;
    const int bgroups = (B + TPB - 1) / TPB;

    // Workspace layout: E (nsteps float4) | Q (nch float4)
    float4* E = (float4*)d_ws;
    float4* Q = (float4*)((char*)d_ws + ((size_t)nsteps * 16 + 255 & ~(size_t)255));

    compute_E<<<(nsteps + TPB - 1) / TPB, TPB, 0, stream>>>(t, w2, g0, gamp, od, E, nsteps);
    chunk_scan<<<1, TPB, 0, stream>>>(E, Q, nsteps, nch);
    propagate<<<nch * bgroups, TPB, 0, stream>>>(E, Q, x0, out, nsteps, B, bgroups);
}